// Round 8
// baseline (518.426 us; speedup 1.0000x reference)
//
#include <hip/hip_runtime.h>
#include <math.h>

// ---------------------------------------------------------------------------
// MultiModalFusionGAT — round 8
//   Projections/epilogue: split-bf16 MFMA, NO LDS (direct global A-fragment
//   loads), 128-row tiles, 32 rows/wave, B-fragment prefetch distance 2.
//   Edge phase: one-pass online-softmax gather (unchanged).
// ---------------------------------------------------------------------------

namespace {
constexpr int HIDN  = 128;
constexpr int NHEAD = 8;

constexpr int NU = 20000, NI = 50000, NT = 50000, NG = 50000;
constexpr int E_TI = 50000, E_IM = 50000, E_UB = 500000, E_BU = 500000;
constexpr int ETOT = E_TI + E_IM + E_UB + E_BU;   // 1,100,000
constexpr int ND   = NI + NU;                     // dst nodes: items then users

constexpr int BASE_U = 0;
constexpr int BASE_I = NU;
constexpr int BASE_T = NU + NI;
constexpr int BASE_G = NU + NI + NT;

constexpr int NMAT = 12;           // 0..3 k, 4..7 v, 8/9 q(user,item), 10/11 Wo(item,user)
constexpr int MATSZ = 128 * 128;

constexpr int TR  = 128;              // rows per block
constexpr int NBU = (NU + TR - 1) / TR;
constexpr int NBI = (NI + TR - 1) / TR;
constexpr int NBT = (NT + TR - 1) / TR;
constexpr int NBG = (NG + TR - 1) / TR;
}

typedef __attribute__((ext_vector_type(8))) short short8v;
typedef __attribute__((ext_vector_type(4))) float f32x4;

__device__ __forceinline__ unsigned short bf16rne(float f) {
    unsigned u = __float_as_uint(f);
    unsigned r = (u + 0x7fffu + ((u >> 16) & 1u)) >> 16;
    return (unsigned short)r;
}
__device__ __forceinline__ float bf16f(unsigned short h) {
    return __uint_as_float(((unsigned)h) << 16);
}
__device__ __forceinline__ float bflo(unsigned int u) { return __uint_as_float(u << 16); }
__device__ __forceinline__ float bfhi(unsigned int u) { return __uint_as_float(u & 0xffff0000u); }

// cw layout: [which(2)][type(4)][row(129)][col(128)]; row 128 = transformed bias
__global__ void build_cw_kernel(const float* __restrict__ Wk, const float* __restrict__ bk,
                                const float* __restrict__ Wv, const float* __restrict__ bv,
                                const float* __restrict__ a_rel, const float* __restrict__ m_rel,
                                float* __restrict__ cw)
{
    const int total = 2 * 4 * 129 * 128;
    int idx = blockIdx.x * blockDim.x + threadIdx.x;
    if (idx >= total) return;
    int c     = idx & 127;
    int r     = (idx >> 7) % 129;
    int t     = ((idx >> 7) / 129) & 3;
    int which = idx / (4 * 129 * 128);
    const int et_map[4] = {2, 3, 0, 1};
    int et = et_map[t];
    const float* W = (which == 0 ? Wk : Wv) + (size_t)t * HIDN * HIDN;
    const float* b = (which == 0 ? bk : bv) + (size_t)t * HIDN;
    const float* A = (which == 0 ? a_rel : m_rel) + (size_t)et * NHEAD * 16 * 16;
    int h = c >> 4, e2 = c & 15;
    float s = 0.f;
#pragma unroll
    for (int d = 0; d < 16; ++d) {
        float w = (r == 128) ? b[h * 16 + d] : W[(size_t)r * HIDN + h * 16 + d];
        s = fmaf(w, A[h * 256 + d * 16 + e2], s);
    }
    cw[idx] = s;
}

__global__ void pack_kernel(const float* __restrict__ cw,
                            const float* __restrict__ Wq, const float* __restrict__ bq,
                            const float* __restrict__ Wo, const float* __restrict__ bo,
                            short* __restrict__ pkh, short* __restrict__ pkl,
                            float* __restrict__ bias)
{
    const int total = NMAT * MATSZ + NMAT * HIDN;
    int idx = blockIdx.x * blockDim.x + threadIdx.x;
    if (idx >= total) return;
    if (idx < NMAT * MATSZ) {
        int mat = idx >> 14;
        int rem = idx & (MATSZ - 1);
        int i    = rem & 7;
        int lane = (rem >> 3) & 63;
        int ct   = (rem >> 9) & 7;
        int ks   = rem >> 12;
        int k   = ks * 32 + ((lane >> 4) & 3) * 8 + i;
        int col = ct * 16 + (lane & 15);
        float v;
        if (mat < 8)       v = cw[(size_t)mat * 129 * 128 + (size_t)k * 128 + col];
        else if (mat < 10) v = Wq[(size_t)(mat - 8) * MATSZ + (size_t)k * 128 + col];
        else               v = Wo[(size_t)(mat - 10) * MATSZ + (size_t)k * 128 + col];
        unsigned short hb = bf16rne(v);
        float rest = v - bf16f(hb);
        pkh[idx] = (short)hb;
        pkl[idx] = (short)bf16rne(rest);
    } else {
        int b = idx - NMAT * MATSZ;
        int mat = b >> 7, col = b & 127;
        float v;
        if (mat < 8)       v = cw[(size_t)mat * 129 * 128 + (size_t)128 * 128 + col];
        else if (mat < 10) v = bq[(mat - 8) * HIDN + col];
        else               v = bo[(mat - 10) * HIDN + col];
        bias[b] = v;
    }
}

// All four node types in one launch; 128-row tiles, 32 rows/wave, no LDS.
__global__ __launch_bounds__(256) void mfma_proj_all(
    const float* __restrict__ xu, const float* __restrict__ xi,
    const float* __restrict__ xt, const float* __restrict__ xg,
    const short* __restrict__ pkh, const short* __restrict__ pkl,
    const float* __restrict__ bias,
    unsigned short* __restrict__ krb, unsigned short* __restrict__ vrb,
    float* __restrict__ q_u, float* __restrict__ q_i)
{
    int b = blockIdx.x;
    int seg, bloc;
    if (b < NBU)                  { seg = 0; bloc = b; }
    else if (b < NBU + NBI)       { seg = 1; bloc = b - NBU; }
    else if (b < NBU + NBI + NBT) { seg = 2; bloc = b - NBU - NBI; }
    else                          { seg = 3; bloc = b - NBU - NBI - NBT; }
    const float* x = (seg == 0) ? xu : (seg == 1) ? xi : (seg == 2) ? xt : xg;
    const int M     = (seg == 0) ? NU : (seg == 1) ? NI : (seg == 2) ? NT : NG;
    const int rbase = (seg == 0) ? BASE_U : (seg == 1) ? BASE_I : (seg == 2) ? BASE_T : BASE_G;
    float* qp = (seg == 0) ? q_u : (seg == 1) ? q_i : nullptr;

    const int t  = threadIdx.x;
    const int r0 = bloc * TR;
    const int l = t & 63, w = t >> 6;
    const int wr0  = w * 32;
    const int kgrp = l >> 4;

    // ---- A fragments straight from global (rows L2-resident) ----
    short8v ahi[2][4], alo[2][4];
#pragma unroll
    for (int fr = 0; fr < 2; ++fr) {
        int arow = r0 + wr0 + fr * 16 + (l & 15);
        if (arow >= M) arow = M - 1;                    // clamp: results unstored
        const float4* xp = (const float4*)(x + (size_t)arow * HIDN);
#pragma unroll
        for (int ks = 0; ks < 4; ++ks) {
            float4 va = xp[ks * 8 + kgrp * 2];
            float4 vb = xp[ks * 8 + kgrp * 2 + 1];
            float vv[8] = {va.x, va.y, va.z, va.w, vb.x, vb.y, vb.z, vb.w};
#pragma unroll
            for (int i = 0; i < 8; ++i) {
                unsigned short hb = bf16rne(vv[i]);
                ahi[fr][ks][i] = (short)hb;
                alo[fr][ks][i] = (short)bf16rne(vv[i] - bf16f(hb));
            }
        }
    }

    for (int mi = 0; mi < 3; ++mi) {
        if (mi == 2 && qp == nullptr) break;
        const int mat = (mi == 0) ? seg : (mi == 1) ? (4 + seg) : (8 + seg);
        const short8v* bh = (const short8v*)(pkh + (size_t)mat * MATSZ);
        const short8v* bl = (const short8v*)(pkl + (size_t)mat * MATSZ);
        const float*   bs = bias + mat * HIDN;

        f32x4 acc[2][8];
        f32x4 z; z[0] = 0.f; z[1] = 0.f; z[2] = 0.f; z[3] = 0.f;
#pragma unroll
        for (int fr = 0; fr < 2; ++fr)
#pragma unroll
            for (int ct = 0; ct < 8; ++ct) acc[fr][ct] = z;

        // B prefetch ring, distance 2.  it = ks*8 + ct (fragment-index order).
        short8v pb1[2], pb2[2];
        pb1[0] = bh[0 * 64 + l]; pb2[0] = bl[0 * 64 + l];
        pb1[1] = bh[1 * 64 + l]; pb2[1] = bl[1 * 64 + l];
#pragma unroll
        for (int it = 0; it < 32; ++it) {
            const int ct = it & 7, ks = it >> 3;
            short8v b1 = pb1[it & 1], b2 = pb2[it & 1];
            if (it + 2 < 32) {
                pb1[it & 1] = bh[(it + 2) * 64 + l];
                pb2[it & 1] = bl[(it + 2) * 64 + l];
            }
#pragma unroll
            for (int fr = 0; fr < 2; ++fr) {
                acc[fr][ct] = __builtin_amdgcn_mfma_f32_16x16x32_bf16(ahi[fr][ks], b1, acc[fr][ct], 0, 0, 0);
                acc[fr][ct] = __builtin_amdgcn_mfma_f32_16x16x32_bf16(alo[fr][ks], b1, acc[fr][ct], 0, 0, 0);
                acc[fr][ct] = __builtin_amdgcn_mfma_f32_16x16x32_bf16(ahi[fr][ks], b2, acc[fr][ct], 0, 0, 0);
            }
        }

        const int ccol = l & 15;
        if (mi < 2) {
            unsigned short* dst = (mi == 0) ? krb : vrb;
#pragma unroll
            for (int fr = 0; fr < 2; ++fr) {
                const int crow0 = wr0 + fr * 16 + kgrp * 4;
#pragma unroll
                for (int ct = 0; ct < 8; ++ct) {
                    float bv = bs[ct * 16 + ccol];
#pragma unroll
                    for (int j = 0; j < 4; ++j) {
                        int grow = r0 + crow0 + j;
                        if (grow < M)
                            dst[(size_t)(rbase + grow) * HIDN + ct * 16 + ccol] = bf16rne(acc[fr][ct][j] + bv);
                    }
                }
            }
        } else {
#pragma unroll
            for (int fr = 0; fr < 2; ++fr) {
                const int crow0 = wr0 + fr * 16 + kgrp * 4;
#pragma unroll
                for (int ct = 0; ct < 8; ++ct) {
                    float bv = bs[ct * 16 + ccol];
#pragma unroll
                    for (int j = 0; j < 4; ++j) {
                        int grow = r0 + crow0 + j;
                        if (grow < M)
                            qp[(size_t)grow * HIDN + ct * 16 + ccol] = acc[fr][ct][j] + bv;
                    }
                }
            }
        }
    }
}

// Both epilogues in one launch; 128-row tiles, 32 rows/wave, no LDS.
__global__ __launch_bounds__(256) void mfma_out_all(
    const float* __restrict__ agg_i, const float* __restrict__ agg_u,
    const short* __restrict__ pkh, const short* __restrict__ pkl,
    const float* __restrict__ bias,
    const float* __restrict__ x_item, const float* __restrict__ x_user,
    const float* __restrict__ skip_ptr,
    float* __restrict__ outp)
{
    int b = blockIdx.x;
    int seg = (b < NBI) ? 0 : 1;
    int bloc = (seg == 0) ? b : b - NBI;
    const float* agg = (seg == 0) ? agg_i : agg_u;
    const float* xin = (seg == 0) ? x_item : x_user;
    const int M = (seg == 0) ? NI : NU;
    const int mat = 10 + seg;
    float* out = (seg == 0) ? outp : outp + (size_t)NI * HIDN;

    const int t  = threadIdx.x;
    const int r0 = bloc * TR;
    const int l = t & 63, w = t >> 6;
    const int wr0  = w * 32;
    const int kgrp = l >> 4;

    short8v ahi[2][4], alo[2][4];
#pragma unroll
    for (int fr = 0; fr < 2; ++fr) {
        int arow = r0 + wr0 + fr * 16 + (l & 15);
        if (arow >= M) arow = M - 1;
        const float4* xp = (const float4*)(agg + (size_t)arow * HIDN);
#pragma unroll
        for (int ks = 0; ks < 4; ++ks) {
            float4 va = xp[ks * 8 + kgrp * 2];
            float4 vb = xp[ks * 8 + kgrp * 2 + 1];
            float vv[8] = {va.x, va.y, va.z, va.w, vb.x, vb.y, vb.z, vb.w};
#pragma unroll
            for (int i = 0; i < 8; ++i) {
                float g = 0.5f * vv[i] * (1.0f + erff(vv[i] * 0.70710678118654752440f));
                unsigned short hb = bf16rne(g);
                ahi[fr][ks][i] = (short)hb;
                alo[fr][ks][i] = (short)bf16rne(g - bf16f(hb));
            }
        }
    }

    const short8v* bh = (const short8v*)(pkh + (size_t)mat * MATSZ);
    const short8v* bl = (const short8v*)(pkl + (size_t)mat * MATSZ);
    const float*   bs = bias + mat * HIDN;

    f32x4 acc[2][8];
    f32x4 z; z[0] = 0.f; z[1] = 0.f; z[2] = 0.f; z[3] = 0.f;
#pragma unroll
    for (int fr = 0; fr < 2; ++fr)
#pragma unroll
        for (int ct = 0; ct < 8; ++ct) acc[fr][ct] = z;

    short8v pb1[2], pb2[2];
    pb1[0] = bh[0 * 64 + l]; pb2[0] = bl[0 * 64 + l];
    pb1[1] = bh[1 * 64 + l]; pb2[1] = bl[1 * 64 + l];
#pragma unroll
    for (int it = 0; it < 32; ++it) {
        const int ct = it & 7, ks = it >> 3;
        short8v b1 = pb1[it & 1], b2 = pb2[it & 1];
        if (it + 2 < 32) {
            pb1[it & 1] = bh[(it + 2) * 64 + l];
            pb2[it & 1] = bl[(it + 2) * 64 + l];
        }
#pragma unroll
        for (int fr = 0; fr < 2; ++fr) {
            acc[fr][ct] = __builtin_amdgcn_mfma_f32_16x16x32_bf16(ahi[fr][ks], b1, acc[fr][ct], 0, 0, 0);
            acc[fr][ct] = __builtin_amdgcn_mfma_f32_16x16x32_bf16(alo[fr][ks], b1, acc[fr][ct], 0, 0, 0);
            acc[fr][ct] = __builtin_amdgcn_mfma_f32_16x16x32_bf16(ahi[fr][ks], b2, acc[fr][ct], 0, 0, 0);
        }
    }

    const float gate = 1.f / (1.f + expf(-skip_ptr[seg]));
    const int ccol = l & 15;
#pragma unroll
    for (int fr = 0; fr < 2; ++fr) {
        const int crow0 = wr0 + fr * 16 + kgrp * 4;
#pragma unroll
        for (int ct = 0; ct < 8; ++ct) {
            float bv = bs[ct * 16 + ccol];
#pragma unroll
            for (int j = 0; j < 4; ++j) {
                int grow = r0 + crow0 + j;
                if (grow < M) {
                    size_t o = (size_t)grow * HIDN + ct * 16 + ccol;
                    out[o] = gate * (acc[fr][ct][j] + bv) + (1.f - gate) * xin[o];
                }
            }
        }
    }
}

// ----------------------- CSR construction -----------------------

__global__ void hist_kernel(const int* __restrict__ ti_dst, const int* __restrict__ im_dst,
                            const int* __restrict__ ub_dst, const int* __restrict__ bu_dst,
                            int* __restrict__ deg)
{
    int i = blockIdx.x * blockDim.x + threadIdx.x;
    if (i >= ETOT) return;
    int d;
    if (i < E_TI)                     d = ti_dst[i];
    else if (i < E_TI + E_IM)         d = im_dst[i - E_TI];
    else if (i < E_TI + E_IM + E_UB)  d = ub_dst[i - E_TI - E_IM];
    else                              d = NI + bu_dst[i - E_TI - E_IM - E_UB];
    atomicAdd(&deg[d], 1);
}

__global__ void scan1_kernel(int* __restrict__ deg, int* __restrict__ tops, int n)
{
    __shared__ int sh[256];
    int i = blockIdx.x * 256 + threadIdx.x;
    int v = (i < n) ? deg[i] : 0;
    sh[threadIdx.x] = v;
    __syncthreads();
    for (int o = 1; o < 256; o <<= 1) {
        int t = (threadIdx.x >= o) ? sh[threadIdx.x - o] : 0;
        __syncthreads();
        sh[threadIdx.x] += t;
        __syncthreads();
    }
    if (i < n) deg[i] = sh[threadIdx.x];
    if (threadIdx.x == 255) tops[blockIdx.x] = sh[255];
}

__global__ void scan2_kernel(int* __restrict__ tops, int nb)
{
    __shared__ int sh[1024];
    int v = (threadIdx.x < nb) ? tops[threadIdx.x] : 0;
    sh[threadIdx.x] = v;
    __syncthreads();
    for (int o = 1; o < 1024; o <<= 1) {
        int t = (threadIdx.x >= o) ? sh[threadIdx.x - o] : 0;
        __syncthreads();
        sh[threadIdx.x] += t;
        __syncthreads();
    }
    if (threadIdx.x < nb) tops[threadIdx.x] = sh[threadIdx.x];
}

__global__ void scan3_kernel(const int* __restrict__ part, const int* __restrict__ tops,
                             int* __restrict__ rowptr, int* __restrict__ cursor, int n)
{
    int i = blockIdx.x * 256 + threadIdx.x;
    if (i >= n) return;
    int add = (blockIdx.x > 0) ? tops[blockIdx.x - 1] : 0;
    int prev = (i > 0) ? ((threadIdx.x > 0) ? part[i - 1] + add
                                            : ((blockIdx.x > 0) ? tops[blockIdx.x - 1] : 0))
                       : 0;
    rowptr[i + 1] = part[i] + add;
    cursor[i] = prev;
    if (i == 0) rowptr[0] = 0;
}

// col entry: (src_row << 2) | edge_type
__global__ void scatter_kernel(const int* __restrict__ ti_src, const int* __restrict__ ti_dst,
                               const int* __restrict__ im_src, const int* __restrict__ im_dst,
                               const int* __restrict__ ub_src, const int* __restrict__ ub_dst,
                               const int* __restrict__ bu_src, const int* __restrict__ bu_dst,
                               int* __restrict__ cursor, int* __restrict__ col)
{
    int i = blockIdx.x * blockDim.x + threadIdx.x;
    if (i >= ETOT) return;
    int d, row, et;
    if (i < E_TI)                    { d = ti_dst[i];                 row = BASE_T + ti_src[i];                 et = 0; }
    else if (i < E_TI + E_IM)        { int e = i - E_TI;              row = BASE_G + im_src[e]; d = im_dst[e];  et = 1; }
    else if (i < E_TI + E_IM + E_UB) { int e = i - E_TI - E_IM;       row = BASE_U + ub_src[e]; d = ub_dst[e];  et = 2; }
    else                             { int e = i - E_TI - E_IM - E_UB; row = BASE_I + bu_src[e]; d = NI + bu_dst[e]; et = 3; }
    int p = atomicAdd(&cursor[d], 1);
    col[p] = (row << 2) | et;
}

// ------------------- fused edge softmax-attention (online, one pass) -------------------
__global__ __launch_bounds__(256) void f12_kernel(
    const int* __restrict__ rowptr, const int* __restrict__ rowend,
    const int* __restrict__ col,
    const unsigned int* __restrict__ krw,   // bf16x2 per uint, row stride 64
    const float* __restrict__ q_i, const float* __restrict__ q_u,
    const unsigned int* __restrict__ vrw,
    const float* __restrict__ prel,
    float* __restrict__ agg_i, float* __restrict__ agg_u)
{
    int wid = (blockIdx.x << 2) + (threadIdx.x >> 6);
    if (wid >= ND) return;
    const int l = threadIdx.x & 63;
    const int h = l >> 3;

    const float* qrow = (wid < NI) ? q_i + (size_t)wid * HIDN
                                   : q_u + (size_t)(wid - NI) * HIDN;
    float2 qv = *(const float2*)(qrow + 2 * l);
    const float pr0 = prel[h]      * 0.25f;
    const float pr1 = prel[8 + h]  * 0.25f;
    const float pr2 = prel[16 + h] * 0.25f;
    const float pr3 = prel[24 + h] * 0.25f;

    const int start = rowptr[wid], end = rowend[wid];
    float m = -3.0e38f, ax = 0.f, ay = 0.f, den = 0.f;

    int p = start;
    for (; p + 1 < end; p += 2) {
        int pk0 = col[p], pk1 = col[p + 1];
        unsigned int u0 = krw[(size_t)(pk0 >> 2) * 64 + l];
        unsigned int u1 = krw[(size_t)(pk1 >> 2) * 64 + l];
        unsigned int v0 = vrw[(size_t)(pk0 >> 2) * 64 + l];
        unsigned int v1 = vrw[(size_t)(pk1 >> 2) * 64 + l];
        float d0 = qv.x * bflo(u0) + qv.y * bfhi(u0);
        float d1 = qv.x * bflo(u1) + qv.y * bfhi(u1);
        d0 += __shfl_xor(d0, 1); d1 += __shfl_xor(d1, 1);
        d0 += __shfl_xor(d0, 2); d1 += __shfl_xor(d1, 2);
        d0 += __shfl_xor(d0, 4); d1 += __shfl_xor(d1, 4);
        int e0t = pk0 & 3, e1t = pk1 & 3;
        float f0 = (e0t & 2) ? ((e0t & 1) ? pr3 : pr2) : ((e0t & 1) ? pr1 : pr0);
        float f1 = (e1t & 2) ? ((e1t & 1) ? pr3 : pr2) : ((e1t & 1) ? pr1 : pr0);
        float a0 = d0 * f0;
        float a1 = d1 * f1;
        float mn = fmaxf(m, fmaxf(a0, a1));
        float s  = __expf(m - mn);
        float e0 = __expf(a0 - mn);
        float e1 = __expf(a1 - mn);
        ax = ax * s + e0 * bflo(v0) + e1 * bflo(v1);
        ay = ay * s + e0 * bfhi(v0) + e1 * bfhi(v1);
        den = den * s + e0 + e1;
        m = mn;
    }
    if (p < end) {
        int pk0 = col[p];
        unsigned int u0 = krw[(size_t)(pk0 >> 2) * 64 + l];
        unsigned int v0 = vrw[(size_t)(pk0 >> 2) * 64 + l];
        float d0 = qv.x * bflo(u0) + qv.y * bfhi(u0);
        d0 += __shfl_xor(d0, 1);
        d0 += __shfl_xor(d0, 2);
        d0 += __shfl_xor(d0, 4);
        int e0t = pk0 & 3;
        float f0 = (e0t & 2) ? ((e0t & 1) ? pr3 : pr2) : ((e0t & 1) ? pr1 : pr0);
        float a0 = d0 * f0;
        float mn = fmaxf(m, a0);
        float s  = __expf(m - mn);
        float e0 = __expf(a0 - mn);
        ax = ax * s + e0 * bflo(v0);
        ay = ay * s + e0 * bfhi(v0);
        den = den * s + e0;
    }

    float inv = 1.f / (den + 1e-16f);
    float* dst = (wid < NI) ? agg_i + (size_t)wid * HIDN
                            : agg_u + (size_t)(wid - NI) * HIDN;
    *(float2*)(dst + 2 * l) = make_float2(ax * inv, ay * inv);
}

extern "C" void kernel_launch(void* const* d_in, const int* in_sizes, int n_in,
                              void* d_out, int out_size, void* d_ws, size_t ws_size,
                              hipStream_t stream)
{
    const float* x_user = (const float*)d_in[0];
    const float* x_item = (const float*)d_in[1];
    const float* x_taste= (const float*)d_in[2];
    const float* x_image= (const float*)d_in[3];
    const float* Wk     = (const float*)d_in[4];
    const float* bk     = (const float*)d_in[5];
    const float* Wq     = (const float*)d_in[6];
    const float* bq     = (const float*)d_in[7];
    const float* Wv     = (const float*)d_in[8];
    const float* bv     = (const float*)d_in[9];
    const float* a_rel  = (const float*)d_in[10];
    const float* m_rel  = (const float*)d_in[11];
    const float* p_rel  = (const float*)d_in[12];
    const float* Wo     = (const float*)d_in[13];
    const float* bo     = (const float*)d_in[14];
    const float* skip   = (const float*)d_in[15];
    const int* ti_src = (const int*)d_in[16];
    const int* ti_dst = (const int*)d_in[17];
    const int* im_src = (const int*)d_in[18];
    const int* im_dst = (const int*)d_in[19];
    const int* ub_src = (const int*)d_in[20];
    const int* ub_dst = (const int*)d_in[21];
    const int* bu_src = (const int*)d_in[22];
    const int* bu_dst = (const int*)d_in[23];

    float* ws = (float*)d_ws;
    float* outp = (float*)d_out;
    (void)in_sizes; (void)n_in; (void)out_size;

    // ---- workspace layout (floats) ----
    size_t off = 0;
    auto alloc = [&](size_t n) { size_t o = off; off += n; return o; };
    const size_t o_cw   = alloc((size_t)2 * 4 * 129 * 128);   // reused as deg[] after pack
    const size_t o_pkh  = alloc((size_t)NMAT * MATSZ / 2);
    const size_t o_pkl  = alloc((size_t)NMAT * MATSZ / 2);
    const size_t o_bias = alloc((size_t)NMAT * HIDN);
    const size_t o_krb  = alloc((size_t)(NU + NI + NT + NG) * HIDN / 2);  // bf16 table
    const size_t o_vrb  = alloc((size_t)(NU + NI + NT + NG) * HIDN / 2);  // bf16 table
    const size_t o_q_i  = alloc((size_t)NI * HIDN);
    const size_t o_q_u  = alloc((size_t)NU * HIDN);
    const size_t o_agg  = alloc((size_t)(NI + NU) * HIDN);
    const size_t o_int  = alloc((size_t)(ND + 1) + ND + 1024 + ETOT);

    if (ws_size < off * sizeof(float)) return;  // clean failure instead of OOB fault

    unsigned short* krb = (unsigned short*)(ws + o_krb);
    unsigned short* vrb = (unsigned short*)(ws + o_vrb);

    short* pkh  = (short*)(ws + o_pkh);
    short* pkl  = (short*)(ws + o_pkl);
    float* bias = ws + o_bias;

    int* deg    = (int*)(ws + o_cw);        // overlays cw (dead after pack)
    int* rowptr = (int*)(ws + o_int);
    int* cursor = rowptr + (ND + 1);
    int* tops   = cursor + ND;
    int* col    = tops + 1024;

    float* agg_i = ws + o_agg;
    float* agg_u = ws + o_agg + (size_t)NI * HIDN;

    // ---- 1. combined weights + MFMA pack ----
    {
        int total = 2 * 4 * 129 * 128;
        build_cw_kernel<<<(total + 255) / 256, 256, 0, stream>>>(
            Wk, bk, Wv, bv, a_rel, m_rel, ws + o_cw);
        int ptotal = NMAT * MATSZ + NMAT * HIDN;
        pack_kernel<<<(ptotal + 255) / 256, 256, 0, stream>>>(
            ws + o_cw, Wq, bq, Wo, bo, pkh, pkl, bias);
    }

    // ---- 2. projections: ONE launch, no-LDS 128-row tiles ----
    mfma_proj_all<<<NBU + NBI + NBT + NBG, 256, 0, stream>>>(
        x_user, x_item, x_taste, x_image, pkh, pkl, bias,
        krb, vrb, ws + o_q_u, ws + o_q_i);

    // ---- 3. CSR build ----
    hipMemsetAsync(deg, 0, ND * sizeof(int), stream);
    hist_kernel<<<(ETOT + 255) / 256, 256, 0, stream>>>(ti_dst, im_dst, ub_dst, bu_dst, deg);
    const int NB1 = (ND + 255) / 256;
    scan1_kernel<<<NB1, 256, 0, stream>>>(deg, tops, ND);
    scan2_kernel<<<1, 1024, 0, stream>>>(tops, NB1);
    scan3_kernel<<<NB1, 256, 0, stream>>>(deg, tops, rowptr, cursor, ND);
    scatter_kernel<<<(ETOT + 255) / 256, 256, 0, stream>>>(
        ti_src, ti_dst, im_src, im_dst, ub_src, ub_dst, bu_src, bu_dst, cursor, col);
    // after scatter, cursor[d] == row end

    // ---- 4. fused online-softmax edge aggregation ----
    const int NBW = (ND + 3) / 4;
    f12_kernel<<<NBW, 256, 0, stream>>>(
        rowptr, cursor, col,
        (const unsigned int*)krb, ws + o_q_i, ws + o_q_u,
        (const unsigned int*)vrb, p_rel,
        agg_i, agg_u);

    // ---- 5. epilogue: ONE launch, no-LDS 128-row tiles ----
    mfma_out_all<<<NBI + NBU, 256, 0, stream>>>(
        agg_i, agg_u, pkh, pkl, bias, x_item, x_user, skip, outp);
}

// Round 9
// 412.372 us; speedup vs baseline: 1.2572x; 1.2572x over previous
//
#include <hip/hip_runtime.h>
#include <math.h>

// ---------------------------------------------------------------------------
// MultiModalFusionGAT — round 9
//   = round 6 structure (64-row LDS tiles, 16 rows/wave, one proj launch,
//     one epilogue launch, one-pass online-softmax edge kernel)
//   + distance-4 B-fragment prefetch ring in the MFMA loops (8 outstanding
//     L2 loads per wave) to cover the ~200cy L2 latency that made round 6's
//     proj 85% stall (MfmaUtil 10%, VALUBusy 10%, VGPR 68 = no prefetch).
// ---------------------------------------------------------------------------

namespace {
constexpr int HIDN  = 128;
constexpr int NHEAD = 8;

constexpr int NU = 20000, NI = 50000, NT = 50000, NG = 50000;
constexpr int E_TI = 50000, E_IM = 50000, E_UB = 500000, E_BU = 500000;
constexpr int ETOT = E_TI + E_IM + E_UB + E_BU;   // 1,100,000
constexpr int ND   = NI + NU;                     // dst nodes: items then users

constexpr int BASE_U = 0;
constexpr int BASE_I = NU;
constexpr int BASE_T = NU + NI;
constexpr int BASE_G = NU + NI + NT;

constexpr int NMAT = 12;           // 0..3 k, 4..7 v, 8/9 q(user,item), 10/11 Wo(item,user)
constexpr int MATSZ = 128 * 128;
constexpr int XP = 132;

constexpr int NBU = (NU + 63) / 64;   // 313
constexpr int NBI = (NI + 63) / 64;   // 782
constexpr int NBT = (NT + 63) / 64;   // 782
constexpr int NBG = (NG + 63) / 64;   // 782
}

typedef __attribute__((ext_vector_type(8))) short short8v;
typedef __attribute__((ext_vector_type(4))) float f32x4;

__device__ __forceinline__ unsigned short bf16rne(float f) {
    unsigned u = __float_as_uint(f);
    unsigned r = (u + 0x7fffu + ((u >> 16) & 1u)) >> 16;
    return (unsigned short)r;
}
__device__ __forceinline__ float bf16f(unsigned short h) {
    return __uint_as_float(((unsigned)h) << 16);
}
__device__ __forceinline__ float bflo(unsigned int u) { return __uint_as_float(u << 16); }
__device__ __forceinline__ float bfhi(unsigned int u) { return __uint_as_float(u & 0xffff0000u); }

// cw layout: [which(2)][type(4)][row(129)][col(128)]; row 128 = transformed bias
__global__ void build_cw_kernel(const float* __restrict__ Wk, const float* __restrict__ bk,
                                const float* __restrict__ Wv, const float* __restrict__ bv,
                                const float* __restrict__ a_rel, const float* __restrict__ m_rel,
                                float* __restrict__ cw)
{
    const int total = 2 * 4 * 129 * 128;
    int idx = blockIdx.x * blockDim.x + threadIdx.x;
    if (idx >= total) return;
    int c     = idx & 127;
    int r     = (idx >> 7) % 129;
    int t     = ((idx >> 7) / 129) & 3;
    int which = idx / (4 * 129 * 128);
    const int et_map[4] = {2, 3, 0, 1};
    int et = et_map[t];
    const float* W = (which == 0 ? Wk : Wv) + (size_t)t * HIDN * HIDN;
    const float* b = (which == 0 ? bk : bv) + (size_t)t * HIDN;
    const float* A = (which == 0 ? a_rel : m_rel) + (size_t)et * NHEAD * 16 * 16;
    int h = c >> 4, e2 = c & 15;
    float s = 0.f;
#pragma unroll
    for (int d = 0; d < 16; ++d) {
        float w = (r == 128) ? b[h * 16 + d] : W[(size_t)r * HIDN + h * 16 + d];
        s = fmaf(w, A[h * 256 + d * 16 + e2], s);
    }
    cw[idx] = s;
}

__global__ void pack_kernel(const float* __restrict__ cw,
                            const float* __restrict__ Wq, const float* __restrict__ bq,
                            const float* __restrict__ Wo, const float* __restrict__ bo,
                            short* __restrict__ pkh, short* __restrict__ pkl,
                            float* __restrict__ bias)
{
    const int total = NMAT * MATSZ + NMAT * HIDN;
    int idx = blockIdx.x * blockDim.x + threadIdx.x;
    if (idx >= total) return;
    if (idx < NMAT * MATSZ) {
        int mat = idx >> 14;
        int rem = idx & (MATSZ - 1);
        int i    = rem & 7;
        int lane = (rem >> 3) & 63;
        int ct   = (rem >> 9) & 7;
        int ks   = rem >> 12;
        int k   = ks * 32 + ((lane >> 4) & 3) * 8 + i;
        int col = ct * 16 + (lane & 15);
        float v;
        if (mat < 8)       v = cw[(size_t)mat * 129 * 128 + (size_t)k * 128 + col];
        else if (mat < 10) v = Wq[(size_t)(mat - 8) * MATSZ + (size_t)k * 128 + col];
        else               v = Wo[(size_t)(mat - 10) * MATSZ + (size_t)k * 128 + col];
        unsigned short hb = bf16rne(v);
        float rest = v - bf16f(hb);
        pkh[idx] = (short)hb;
        pkl[idx] = (short)bf16rne(rest);
    } else {
        int b = idx - NMAT * MATSZ;
        int mat = b >> 7, col = b & 127;
        float v;
        if (mat < 8)       v = cw[(size_t)mat * 129 * 128 + (size_t)128 * 128 + col];
        else if (mat < 10) v = bq[(mat - 8) * HIDN + col];
        else               v = bo[(mat - 10) * HIDN + col];
        bias[b] = v;
    }
}

// All four node types in one launch; 64-row tiles, 16 rows/wave, B prefetch ring.
__global__ __launch_bounds__(256) void mfma_proj_all(
    const float* __restrict__ xu, const float* __restrict__ xi,
    const float* __restrict__ xt, const float* __restrict__ xg,
    const short* __restrict__ pkh, const short* __restrict__ pkl,
    const float* __restrict__ bias,
    unsigned short* __restrict__ krb, unsigned short* __restrict__ vrb,
    float* __restrict__ q_u, float* __restrict__ q_i)
{
    int b = blockIdx.x;
    int seg, bloc;
    if (b < NBU)                  { seg = 0; bloc = b; }
    else if (b < NBU + NBI)       { seg = 1; bloc = b - NBU; }
    else if (b < NBU + NBI + NBT) { seg = 2; bloc = b - NBU - NBI; }
    else                          { seg = 3; bloc = b - NBU - NBI - NBT; }
    const float* x = (seg == 0) ? xu : (seg == 1) ? xi : (seg == 2) ? xt : xg;
    const int M     = (seg == 0) ? NU : (seg == 1) ? NI : (seg == 2) ? NT : NG;
    const int rbase = (seg == 0) ? BASE_U : (seg == 1) ? BASE_I : (seg == 2) ? BASE_T : BASE_G;
    float* qp = (seg == 0) ? q_u : (seg == 1) ? q_i : nullptr;

    __shared__ float xs[64 * XP];
    const int t  = threadIdx.x;
    const int r0 = bloc * 64;
    const int rows = min(64, M - r0);

#pragma unroll
    for (int p = 0; p < 8; ++p) {
        int f = p * 256 + t;
        int row = f >> 5, c4 = f & 31;
        float4 v = make_float4(0.f, 0.f, 0.f, 0.f);
        if (row < rows) v = *(const float4*)(x + (size_t)(r0 + row) * HIDN + c4 * 4);
        *(float4*)&xs[row * XP + c4 * 4] = v;
    }
    __syncthreads();

    const int l = t & 63, w = t >> 6;
    const int arow = w * 16 + (l & 15);
    const int kgrp = l >> 4;

    short8v ahi[4], alo[4];
#pragma unroll
    for (int ks = 0; ks < 4; ++ks) {
        const float* xp = &xs[arow * XP + ks * 32 + kgrp * 8];
        float4 va = *(const float4*)xp;
        float4 vb = *(const float4*)(xp + 4);
        float vv[8] = {va.x, va.y, va.z, va.w, vb.x, vb.y, vb.z, vb.w};
#pragma unroll
        for (int i = 0; i < 8; ++i) {
            unsigned short hb = bf16rne(vv[i]);
            ahi[ks][i] = (short)hb;
            alo[ks][i] = (short)bf16rne(vv[i] - bf16f(hb));
        }
    }

    for (int mi = 0; mi < 3; ++mi) {
        if (mi == 2 && qp == nullptr) break;
        const int mat = (mi == 0) ? seg : (mi == 1) ? (4 + seg) : (8 + seg);
        const short8v* bh = (const short8v*)(pkh + (size_t)mat * MATSZ);
        const short8v* bl = (const short8v*)(pkl + (size_t)mat * MATSZ);
        const float*   bs = bias + mat * HIDN;

        f32x4 acc[8];
        f32x4 z; z[0] = 0.f; z[1] = 0.f; z[2] = 0.f; z[3] = 0.f;
#pragma unroll
        for (int ct = 0; ct < 8; ++ct) acc[ct] = z;

        // B prefetch ring, distance 4 (8 outstanding loads). it = ks*8 + ct.
        short8v pb1[4], pb2[4];
#pragma unroll
        for (int pi = 0; pi < 4; ++pi) {
            pb1[pi] = bh[pi * 64 + l];
            pb2[pi] = bl[pi * 64 + l];
        }
#pragma unroll
        for (int it = 0; it < 32; ++it) {
            const int ks = it >> 3, ct = it & 7;
            short8v b1 = pb1[it & 3], b2 = pb2[it & 3];
            if (it + 4 < 32) {
                pb1[it & 3] = bh[(it + 4) * 64 + l];
                pb2[it & 3] = bl[(it + 4) * 64 + l];
            }
            acc[ct] = __builtin_amdgcn_mfma_f32_16x16x32_bf16(ahi[ks], b1, acc[ct], 0, 0, 0);
            acc[ct] = __builtin_amdgcn_mfma_f32_16x16x32_bf16(alo[ks], b1, acc[ct], 0, 0, 0);
            acc[ct] = __builtin_amdgcn_mfma_f32_16x16x32_bf16(ahi[ks], b2, acc[ct], 0, 0, 0);
        }

        const int crow0 = w * 16 + kgrp * 4;
        const int ccol  = l & 15;
        if (mi < 2) {
            unsigned short* dst = (mi == 0) ? krb : vrb;
#pragma unroll
            for (int ct = 0; ct < 8; ++ct) {
                float bv = bs[ct * 16 + ccol];
#pragma unroll
                for (int j = 0; j < 4; ++j) {
                    int grow = r0 + crow0 + j;
                    if (grow < M)
                        dst[(size_t)(rbase + grow) * HIDN + ct * 16 + ccol] = bf16rne(acc[ct][j] + bv);
                }
            }
        } else {
#pragma unroll
            for (int ct = 0; ct < 8; ++ct) {
                float bv = bs[ct * 16 + ccol];
#pragma unroll
                for (int j = 0; j < 4; ++j) {
                    int grow = r0 + crow0 + j;
                    if (grow < M)
                        qp[(size_t)grow * HIDN + ct * 16 + ccol] = acc[ct][j] + bv;
                }
            }
        }
    }
}

// Both epilogues in one launch: seg0 item (mat 10), seg1 user (mat 11).
__global__ __launch_bounds__(256) void mfma_out_all(
    const float* __restrict__ agg_i, const float* __restrict__ agg_u,
    const short* __restrict__ pkh, const short* __restrict__ pkl,
    const float* __restrict__ bias,
    const float* __restrict__ x_item, const float* __restrict__ x_user,
    const float* __restrict__ skip_ptr,
    float* __restrict__ outp)
{
    int b = blockIdx.x;
    int seg = (b < NBI) ? 0 : 1;
    int bloc = (seg == 0) ? b : b - NBI;
    const float* agg = (seg == 0) ? agg_i : agg_u;
    const float* xin = (seg == 0) ? x_item : x_user;
    const int M = (seg == 0) ? NI : NU;
    const int mat = 10 + seg;
    float* out = (seg == 0) ? outp : outp + (size_t)NI * HIDN;

    __shared__ float xs[64 * XP];
    const int t  = threadIdx.x;
    const int r0 = bloc * 64;
    const int rows = min(64, M - r0);

#pragma unroll
    for (int p = 0; p < 8; ++p) {
        int f = p * 256 + t;
        int row = f >> 5, c4 = f & 31;
        float4 v = make_float4(0.f, 0.f, 0.f, 0.f);
        if (row < rows) v = *(const float4*)(agg + (size_t)(r0 + row) * HIDN + c4 * 4);
        *(float4*)&xs[row * XP + c4 * 4] = v;
    }
    __syncthreads();

    const int l = t & 63, w = t >> 6;
    const int arow = w * 16 + (l & 15);
    const int kgrp = l >> 4;

    short8v ahi[4], alo[4];
#pragma unroll
    for (int ks = 0; ks < 4; ++ks) {
        const float* xp = &xs[arow * XP + ks * 32 + kgrp * 8];
        float4 va = *(const float4*)xp;
        float4 vb = *(const float4*)(xp + 4);
        float vv[8] = {va.x, va.y, va.z, va.w, vb.x, vb.y, vb.z, vb.w};
#pragma unroll
        for (int i = 0; i < 8; ++i) {
            float g = 0.5f * vv[i] * (1.0f + erff(vv[i] * 0.70710678118654752440f));
            unsigned short hb = bf16rne(g);
            ahi[ks][i] = (short)hb;
            alo[ks][i] = (short)bf16rne(g - bf16f(hb));
        }
    }

    const short8v* bh = (const short8v*)(pkh + (size_t)mat * MATSZ);
    const short8v* bl = (const short8v*)(pkl + (size_t)mat * MATSZ);
    const float*   bs = bias + mat * HIDN;

    f32x4 acc[8];
    f32x4 z; z[0] = 0.f; z[1] = 0.f; z[2] = 0.f; z[3] = 0.f;
#pragma unroll
    for (int ct = 0; ct < 8; ++ct) acc[ct] = z;

    short8v pb1[4], pb2[4];
#pragma unroll
    for (int pi = 0; pi < 4; ++pi) {
        pb1[pi] = bh[pi * 64 + l];
        pb2[pi] = bl[pi * 64 + l];
    }
#pragma unroll
    for (int it = 0; it < 32; ++it) {
        const int ks = it >> 3, ct = it & 7;
        short8v b1 = pb1[it & 3], b2 = pb2[it & 3];
        if (it + 4 < 32) {
            pb1[it & 3] = bh[(it + 4) * 64 + l];
            pb2[it & 3] = bl[(it + 4) * 64 + l];
        }
        acc[ct] = __builtin_amdgcn_mfma_f32_16x16x32_bf16(ahi[ks], b1, acc[ct], 0, 0, 0);
        acc[ct] = __builtin_amdgcn_mfma_f32_16x16x32_bf16(alo[ks], b1, acc[ct], 0, 0, 0);
        acc[ct] = __builtin_amdgcn_mfma_f32_16x16x32_bf16(ahi[ks], b2, acc[ct], 0, 0, 0);
    }

    const float gate = 1.f / (1.f + expf(-skip_ptr[seg]));
    const int crow0 = w * 16 + kgrp * 4;
    const int ccol  = l & 15;
#pragma unroll
    for (int ct = 0; ct < 8; ++ct) {
        float bv = bs[ct * 16 + ccol];
#pragma unroll
        for (int j = 0; j < 4; ++j) {
            int grow = r0 + crow0 + j;
            if (grow < M) {
                size_t o = (size_t)grow * HIDN + ct * 16 + ccol;
                out[o] = gate * (acc[ct][j] + bv) + (1.f - gate) * xin[o];
            }
        }
    }
}

// ----------------------- CSR construction -----------------------

__global__ void hist_kernel(const int* __restrict__ ti_dst, const int* __restrict__ im_dst,
                            const int* __restrict__ ub_dst, const int* __restrict__ bu_dst,
                            int* __restrict__ deg)
{
    int i = blockIdx.x * blockDim.x + threadIdx.x;
    if (i >= ETOT) return;
    int d;
    if (i < E_TI)                     d = ti_dst[i];
    else if (i < E_TI + E_IM)         d = im_dst[i - E_TI];
    else if (i < E_TI + E_IM + E_UB)  d = ub_dst[i - E_TI - E_IM];
    else                              d = NI + bu_dst[i - E_TI - E_IM - E_UB];
    atomicAdd(&deg[d], 1);
}

__global__ void scan1_kernel(int* __restrict__ deg, int* __restrict__ tops, int n)
{
    __shared__ int sh[256];
    int i = blockIdx.x * 256 + threadIdx.x;
    int v = (i < n) ? deg[i] : 0;
    sh[threadIdx.x] = v;
    __syncthreads();
    for (int o = 1; o < 256; o <<= 1) {
        int t = (threadIdx.x >= o) ? sh[threadIdx.x - o] : 0;
        __syncthreads();
        sh[threadIdx.x] += t;
        __syncthreads();
    }
    if (i < n) deg[i] = sh[threadIdx.x];
    if (threadIdx.x == 255) tops[blockIdx.x] = sh[255];
}

__global__ void scan2_kernel(int* __restrict__ tops, int nb)
{
    __shared__ int sh[1024];
    int v = (threadIdx.x < nb) ? tops[threadIdx.x] : 0;
    sh[threadIdx.x] = v;
    __syncthreads();
    for (int o = 1; o < 1024; o <<= 1) {
        int t = (threadIdx.x >= o) ? sh[threadIdx.x - o] : 0;
        __syncthreads();
        sh[threadIdx.x] += t;
        __syncthreads();
    }
    if (threadIdx.x < nb) tops[threadIdx.x] = sh[threadIdx.x];
}

__global__ void scan3_kernel(const int* __restrict__ part, const int* __restrict__ tops,
                             int* __restrict__ rowptr, int* __restrict__ cursor, int n)
{
    int i = blockIdx.x * 256 + threadIdx.x;
    if (i >= n) return;
    int add = (blockIdx.x > 0) ? tops[blockIdx.x - 1] : 0;
    int prev = (i > 0) ? ((threadIdx.x > 0) ? part[i - 1] + add
                                            : ((blockIdx.x > 0) ? tops[blockIdx.x - 1] : 0))
                       : 0;
    rowptr[i + 1] = part[i] + add;
    cursor[i] = prev;
    if (i == 0) rowptr[0] = 0;
}

// col entry: (src_row << 2) | edge_type
__global__ void scatter_kernel(const int* __restrict__ ti_src, const int* __restrict__ ti_dst,
                               const int* __restrict__ im_src, const int* __restrict__ im_dst,
                               const int* __restrict__ ub_src, const int* __restrict__ ub_dst,
                               const int* __restrict__ bu_src, const int* __restrict__ bu_dst,
                               int* __restrict__ cursor, int* __restrict__ col)
{
    int i = blockIdx.x * blockDim.x + threadIdx.x;
    if (i >= ETOT) return;
    int d, row, et;
    if (i < E_TI)                    { d = ti_dst[i];                 row = BASE_T + ti_src[i];                 et = 0; }
    else if (i < E_TI + E_IM)        { int e = i - E_TI;              row = BASE_G + im_src[e]; d = im_dst[e];  et = 1; }
    else if (i < E_TI + E_IM + E_UB) { int e = i - E_TI - E_IM;       row = BASE_U + ub_src[e]; d = ub_dst[e];  et = 2; }
    else                             { int e = i - E_TI - E_IM - E_UB; row = BASE_I + bu_src[e]; d = NI + bu_dst[e]; et = 3; }
    int p = atomicAdd(&cursor[d], 1);
    col[p] = (row << 2) | et;
}

// ------------------- fused edge softmax-attention (online, one pass) -------------------
__global__ __launch_bounds__(256) void f12_kernel(
    const int* __restrict__ rowptr, const int* __restrict__ rowend,
    const int* __restrict__ col,
    const unsigned int* __restrict__ krw,   // bf16x2 per uint, row stride 64
    const float* __restrict__ q_i, const float* __restrict__ q_u,
    const unsigned int* __restrict__ vrw,
    const float* __restrict__ prel,
    float* __restrict__ agg_i, float* __restrict__ agg_u)
{
    int wid = (blockIdx.x << 2) + (threadIdx.x >> 6);
    if (wid >= ND) return;
    const int l = threadIdx.x & 63;
    const int h = l >> 3;

    const float* qrow = (wid < NI) ? q_i + (size_t)wid * HIDN
                                   : q_u + (size_t)(wid - NI) * HIDN;
    float2 qv = *(const float2*)(qrow + 2 * l);
    const float pr0 = prel[h]      * 0.25f;
    const float pr1 = prel[8 + h]  * 0.25f;
    const float pr2 = prel[16 + h] * 0.25f;
    const float pr3 = prel[24 + h] * 0.25f;

    const int start = rowptr[wid], end = rowend[wid];
    float m = -3.0e38f, ax = 0.f, ay = 0.f, den = 0.f;

    int p = start;
    for (; p + 1 < end; p += 2) {
        int pk0 = col[p], pk1 = col[p + 1];
        unsigned int u0 = krw[(size_t)(pk0 >> 2) * 64 + l];
        unsigned int u1 = krw[(size_t)(pk1 >> 2) * 64 + l];
        unsigned int v0 = vrw[(size_t)(pk0 >> 2) * 64 + l];
        unsigned int v1 = vrw[(size_t)(pk1 >> 2) * 64 + l];
        float d0 = qv.x * bflo(u0) + qv.y * bfhi(u0);
        float d1 = qv.x * bflo(u1) + qv.y * bfhi(u1);
        d0 += __shfl_xor(d0, 1); d1 += __shfl_xor(d1, 1);
        d0 += __shfl_xor(d0, 2); d1 += __shfl_xor(d1, 2);
        d0 += __shfl_xor(d0, 4); d1 += __shfl_xor(d1, 4);
        int e0t = pk0 & 3, e1t = pk1 & 3;
        float f0 = (e0t & 2) ? ((e0t & 1) ? pr3 : pr2) : ((e0t & 1) ? pr1 : pr0);
        float f1 = (e1t & 2) ? ((e1t & 1) ? pr3 : pr2) : ((e1t & 1) ? pr1 : pr0);
        float a0 = d0 * f0;
        float a1 = d1 * f1;
        float mn = fmaxf(m, fmaxf(a0, a1));
        float s  = __expf(m - mn);
        float e0 = __expf(a0 - mn);
        float e1 = __expf(a1 - mn);
        ax = ax * s + e0 * bflo(v0) + e1 * bflo(v1);
        ay = ay * s + e0 * bfhi(v0) + e1 * bfhi(v1);
        den = den * s + e0 + e1;
        m = mn;
    }
    if (p < end) {
        int pk0 = col[p];
        unsigned int u0 = krw[(size_t)(pk0 >> 2) * 64 + l];
        unsigned int v0 = vrw[(size_t)(pk0 >> 2) * 64 + l];
        float d0 = qv.x * bflo(u0) + qv.y * bfhi(u0);
        d0 += __shfl_xor(d0, 1);
        d0 += __shfl_xor(d0, 2);
        d0 += __shfl_xor(d0, 4);
        int e0t = pk0 & 3;
        float f0 = (e0t & 2) ? ((e0t & 1) ? pr3 : pr2) : ((e0t & 1) ? pr1 : pr0);
        float a0 = d0 * f0;
        float mn = fmaxf(m, a0);
        float s  = __expf(m - mn);
        float e0 = __expf(a0 - mn);
        ax = ax * s + e0 * bflo(v0);
        ay = ay * s + e0 * bfhi(v0);
        den = den * s + e0;
    }

    float inv = 1.f / (den + 1e-16f);
    float* dst = (wid < NI) ? agg_i + (size_t)wid * HIDN
                            : agg_u + (size_t)(wid - NI) * HIDN;
    *(float2*)(dst + 2 * l) = make_float2(ax * inv, ay * inv);
}

extern "C" void kernel_launch(void* const* d_in, const int* in_sizes, int n_in,
                              void* d_out, int out_size, void* d_ws, size_t ws_size,
                              hipStream_t stream)
{
    const float* x_user = (const float*)d_in[0];
    const float* x_item = (const float*)d_in[1];
    const float* x_taste= (const float*)d_in[2];
    const float* x_image= (const float*)d_in[3];
    const float* Wk     = (const float*)d_in[4];
    const float* bk     = (const float*)d_in[5];
    const float* Wq     = (const float*)d_in[6];
    const float* bq     = (const float*)d_in[7];
    const float* Wv     = (const float*)d_in[8];
    const float* bv     = (const float*)d_in[9];
    const float* a_rel  = (const float*)d_in[10];
    const float* m_rel  = (const float*)d_in[11];
    const float* p_rel  = (const float*)d_in[12];
    const float* Wo     = (const float*)d_in[13];
    const float* bo     = (const float*)d_in[14];
    const float* skip   = (const float*)d_in[15];
    const int* ti_src = (const int*)d_in[16];
    const int* ti_dst = (const int*)d_in[17];
    const int* im_src = (const int*)d_in[18];
    const int* im_dst = (const int*)d_in[19];
    const int* ub_src = (const int*)d_in[20];
    const int* ub_dst = (const int*)d_in[21];
    const int* bu_src = (const int*)d_in[22];
    const int* bu_dst = (const int*)d_in[23];

    float* ws = (float*)d_ws;
    float* outp = (float*)d_out;
    (void)in_sizes; (void)n_in; (void)out_size;

    // ---- workspace layout (floats) ----
    size_t off = 0;
    auto alloc = [&](size_t n) { size_t o = off; off += n; return o; };
    const size_t o_cw   = alloc((size_t)2 * 4 * 129 * 128);   // reused as deg[] after pack
    const size_t o_pkh  = alloc((size_t)NMAT * MATSZ / 2);
    const size_t o_pkl  = alloc((size_t)NMAT * MATSZ / 2);
    const size_t o_bias = alloc((size_t)NMAT * HIDN);
    const size_t o_krb  = alloc((size_t)(NU + NI + NT + NG) * HIDN / 2);  // bf16 table
    const size_t o_vrb  = alloc((size_t)(NU + NI + NT + NG) * HIDN / 2);  // bf16 table
    const size_t o_q_i  = alloc((size_t)NI * HIDN);
    const size_t o_q_u  = alloc((size_t)NU * HIDN);
    const size_t o_agg  = alloc((size_t)(NI + NU) * HIDN);
    const size_t o_int  = alloc((size_t)(ND + 1) + ND + 1024 + ETOT);

    if (ws_size < off * sizeof(float)) return;  // clean failure instead of OOB fault

    unsigned short* krb = (unsigned short*)(ws + o_krb);
    unsigned short* vrb = (unsigned short*)(ws + o_vrb);

    short* pkh  = (short*)(ws + o_pkh);
    short* pkl  = (short*)(ws + o_pkl);
    float* bias = ws + o_bias;

    int* deg    = (int*)(ws + o_cw);        // overlays cw (dead after pack)
    int* rowptr = (int*)(ws + o_int);
    int* cursor = rowptr + (ND + 1);
    int* tops   = cursor + ND;
    int* col    = tops + 1024;

    float* agg_i = ws + o_agg;
    float* agg_u = ws + o_agg + (size_t)NI * HIDN;

    // ---- 1. combined weights + MFMA pack ----
    {
        int total = 2 * 4 * 129 * 128;
        build_cw_kernel<<<(total + 255) / 256, 256, 0, stream>>>(
            Wk, bk, Wv, bv, a_rel, m_rel, ws + o_cw);
        int ptotal = NMAT * MATSZ + NMAT * HIDN;
        pack_kernel<<<(ptotal + 255) / 256, 256, 0, stream>>>(
            ws + o_cw, Wq, bq, Wo, bo, pkh, pkl, bias);
    }

    // ---- 2. projections: ONE launch, 64-row LDS tiles + B prefetch ring ----
    mfma_proj_all<<<NBU + NBI + NBT + NBG, 256, 0, stream>>>(
        x_user, x_item, x_taste, x_image, pkh, pkl, bias,
        krb, vrb, ws + o_q_u, ws + o_q_i);

    // ---- 3. CSR build ----
    hipMemsetAsync(deg, 0, ND * sizeof(int), stream);
    hist_kernel<<<(ETOT + 255) / 256, 256, 0, stream>>>(ti_dst, im_dst, ub_dst, bu_dst, deg);
    const int NB1 = (ND + 255) / 256;
    scan1_kernel<<<NB1, 256, 0, stream>>>(deg, tops, ND);
    scan2_kernel<<<1, 1024, 0, stream>>>(tops, NB1);
    scan3_kernel<<<NB1, 256, 0, stream>>>(deg, tops, rowptr, cursor, ND);
    scatter_kernel<<<(ETOT + 255) / 256, 256, 0, stream>>>(
        ti_src, ti_dst, im_src, im_dst, ub_src, ub_dst, bu_src, bu_dst, cursor, col);
    // after scatter, cursor[d] == row end

    // ---- 4. fused online-softmax edge aggregation ----
    const int NBW = (ND + 3) / 4;
    f12_kernel<<<NBW, 256, 0, stream>>>(
        rowptr, cursor, col,
        (const unsigned int*)krb, ws + o_q_i, ws + o_q_u,
        (const unsigned int*)vrb, p_rel,
        agg_i, agg_u);

    // ---- 5. epilogue: ONE launch, 64-row tiles + B prefetch ring ----
    mfma_out_all<<<NBI + NBU, 256, 0, stream>>>(
        agg_i, agg_u, pkh, pkl, bias, x_item, x_user, skip, outp);
}